// Round 3
// baseline (245.623 us; speedup 1.0000x reference)
//
#include <hip/hip_runtime.h>

// Reference reduces to: out = box3x3_zeropad(x) + x + bias[c]
// (softmax over a size-1 axis == 1.0; the w1/w2 matmul branch is dead).
//
// x: (32, 256, 64, 64) fp32 -> 8192 planes of 64x64. Pure memory-bound
// stencil; traffic floor ~276 MB -> ~44 us at 6.3 TB/s.
//
// R2 postmortem: LDS-staged version hit 82.5 us (3.3 TB/s). Compute-phase
// ds_read_b128 start-banks collapsed to {0,8,16,24} (SMW=72 == 8 mod 32)
// -> ~2x LDS serialization, phase-locked with HBM time. This version
// deletes LDS/barriers entirely: register sliding window down the rows,
// horizontal neighbors via DPP row_shr/row_shl within 16-lane rows
// (bound_ctrl=1 zero-fill == the conv's zero padding at plane edges).
//
// Layout: wave = 4 planes (16 lanes x float4 = one 64-col row each).
// Each wave marches a 32-row band. 1024 blocks x 256 threads.

#define HH 64
#define WW 64

__device__ __forceinline__ float dpp_shr1(float x) {
    // lane i <- lane i-1 within each 16-lane DPP row; lane 0 of row -> 0
    return __int_as_float(__builtin_amdgcn_update_dpp(
        0, __float_as_int(x), 0x111, 0xF, 0xF, true));
}
__device__ __forceinline__ float dpp_shl1(float x) {
    // lane i <- lane i+1 within each 16-lane DPP row; lane 15 of row -> 0
    return __int_as_float(__builtin_amdgcn_update_dpp(
        0, __float_as_int(x), 0x101, 0xF, 0xF, true));
}

// horizontal 3-tap box sum of a row held as lane-distributed float4s
__device__ __forceinline__ float4 hsum3(float4 v) {
    float lft = dpp_shr1(v.w);   // col-1 (left neighbor's .w; 0 at plane edge)
    float rgt = dpp_shl1(v.x);   // col+4 (right neighbor's .x; 0 at plane edge)
    float t1 = v.x + v.y;
    float t2 = v.y + v.z;
    float t3 = v.z + v.w;
    float4 h;
    h.x = lft + t1;      // v[-1]+v[0]+v[1]
    h.y = t1 + v.z;      // v[0]+v[1]+v[2]
    h.z = t2 + v.w;      // v[1]+v[2]+v[3]
    h.w = t3 + rgt;      // v[2]+v[3]+v[4]
    return h;
}

__global__ __launch_bounds__(256) void dwconv_march_kernel(
    const float* __restrict__ x,
    const float* __restrict__ bias,
    float* __restrict__ out)
{
    const int bid  = blockIdx.x;          // 0..1023
    const int pset = bid >> 1;            // 0..511, 16 planes each
    const int band = bid & 1;             // 0: rows 0..31, 1: rows 32..63
    const int wv   = threadIdx.x >> 6;    // wave in block, 0..3
    const int lane = threadIdx.x & 63;
    const int grp  = lane >> 4;           // plane within wave, 0..3
    const int l16  = lane & 15;           // float4 segment within row

    const int plane = pset * 16 + wv * 4 + grp;   // 0..8191
    const float bv  = bias[plane & 255];

    const int r0 = band << 5;             // first output row of this band
    const float* xp = x   + (size_t)plane * (HH * WW) + (size_t)r0 * WW + (l16 << 2);
    float*       op = out + (size_t)plane * (HH * WW) + (size_t)r0 * WW + (l16 << 2);

    float4 hA, hB, xbB;

    // row r0-1 -> hA (zero-pad above plane)
    if (band == 0) {
        hA = make_float4(0.f, 0.f, 0.f, 0.f);
    } else {
        float4 vA = *reinterpret_cast<const float4*>(xp - WW);
        hA = hsum3(vA);
    }
    // row r0 -> hB, xbB = x + bias
    {
        float4 vB = *reinterpret_cast<const float4*>(xp);
        hB  = hsum3(vB);
        xbB = make_float4(vB.x + bv, vB.y + bv, vB.z + bv, vB.w + bv);
    }

    // output rows r0 .. r0+30 (row r0+i+1 always exists: r0+31 <= 63)
    #pragma unroll 4
    for (int i = 0; i < 31; ++i) {
        float4 vC = *reinterpret_cast<const float4*>(xp + (i + 1) * WW);
        float4 hC = hsum3(vC);
        float4 o;
        o.x = hA.x + hB.x + hC.x + xbB.x;
        o.y = hA.y + hB.y + hC.y + xbB.y;
        o.z = hA.z + hB.z + hC.z + xbB.z;
        o.w = hA.w + hB.w + hC.w + xbB.w;
        *reinterpret_cast<float4*>(op + i * WW) = o;
        hA = hB;
        hB = hC;
        xbB = make_float4(vC.x + bv, vC.y + bv, vC.z + bv, vC.w + bv);
    }

    // last output row r0+31: row below is row 32 (valid, band 0) or row 64 (zero-pad)
    float4 hC;
    if (band == 0) {
        float4 vC = *reinterpret_cast<const float4*>(xp + 32 * WW);
        hC = hsum3(vC);
    } else {
        hC = make_float4(0.f, 0.f, 0.f, 0.f);
    }
    float4 o;
    o.x = hA.x + hB.x + hC.x + xbB.x;
    o.y = hA.y + hB.y + hC.y + xbB.y;
    o.z = hA.z + hB.z + hC.z + xbB.z;
    o.w = hA.w + hB.w + hC.w + xbB.w;
    *reinterpret_cast<float4*>(op + 31 * WW) = o;
}

extern "C" void kernel_launch(void* const* d_in, const int* in_sizes, int n_in,
                              void* d_out, int out_size, void* d_ws, size_t ws_size,
                              hipStream_t stream)
{
    const float* x    = (const float*)d_in[0];
    // d_in[1..4] = w1, b1, w2, b2 : algebraically dead (softmax over size-1 axis == 1)
    const float* bias = (const float*)d_in[5];
    float* out        = (float*)d_out;

    // 8192 planes / 16 planes-per-block * 2 bands = 1024 blocks
    dwconv_march_kernel<<<1024, 256, 0, stream>>>(x, bias, out);
}